// Round 6
// baseline (1932.060 us; speedup 1.0000x reference)
//
#include <hip/hip_runtime.h>
#include <hip/hip_bf16.h>
#include <math.h>

#define BN_EPS 1e-3f
#define SLOPE  0.1f
#define TEMP   5.0f
#define DDIM   3136            // 64 * 49
#define DDIMP  3200            // padded d for k_mu M-blocking (25 * 128)

typedef __attribute__((ext_vector_type(8))) short bf16x8;
typedef __attribute__((ext_vector_type(4))) float f32x4;

static __device__ __forceinline__ short f2b(float f) {
  __hip_bfloat16 h = __float2bfloat16(f);
  return *reinterpret_cast<short*>(&h);
}

// ---- workspace layout (in float slots) ----
#define W2B_OFF   0u                           // w2b bf16, 204800 shorts
#define W1B_OFF   102400u                      // w1b bf16, 4096 shorts
#define DB_OFF    204800u                      // data bf16 [8192][3136]
#define DB_SZ     (8192u*3136u/2u)             // 12845056
#define DT_OFF    (DB_OFF + DB_SZ)             // dataT bf16 [3200][8192] (pad rows stale)
#define DT_SZ     (3200u*8192u/2u)             // 13107200
#define MUB_OFF   (DT_OFF + DT_SZ)             // mu bf16 [112][3136]
#define MUB_SZ    (112u*3136u/2u)
#define MUF_OFF   (MUB_OFF + MUB_SZ)           // mu fp32 [100][3136]
#define MUF_SZ    (100u*3136u)
#define CMS_OFF   (MUF_OFF + MUF_SZ)           // cms bf16 [16][3200][112]
#define CMS_SZ    (16u*3200u*112u/2u)          // 2867200
#define RT_OFF    (CMS_OFF + CMS_SZ)           // rT bf16 [112][8192]
#define RT_SZ     (112u*8192u/2u)
#define CR_OFF    (RT_OFF + RT_SZ)             // crbuf fp32 [12][128]

// ---------------------------------------------------------------------------
// w2 (64,128,5,5) fp32 -> bf16 MFMA-fragment order.
// ---------------------------------------------------------------------------
__global__ __launch_bounds__(256) void k_w2b(const float* __restrict__ w2,
                                             __hip_bfloat16* __restrict__ w2b) {
  int idx = blockIdx.x * 256 + threadIdx.x;   // 204800 total
  if (idx >= 204800) return;
  int ci   = idx & 31;
  int lr   = (idx >> 5) & 15;
  int rest = idx >> 9;            // 0..399
  int kk   = rest % 100;
  int oct  = rest / 100;
  int oc   = oct * 16 + lr;
  int tap  = kk >> 2;
  int c    = ((kk & 3) << 5) + ci;
  w2b[idx] = __float2bfloat16(w2[(oc * 128 + c) * 25 + tap]);
}

// ---------------------------------------------------------------------------
// w1 (128,1,5,5) fp32 -> bf16 frag order: w1b[oct][lr][k], k=tap (25..31 -> 0)
// ---------------------------------------------------------------------------
__global__ __launch_bounds__(256) void k_w1b(const float* __restrict__ w1,
                                             __hip_bfloat16* __restrict__ w1b) {
  int idx = blockIdx.x * 256 + threadIdx.x;   // 4096 total
  if (idx >= 4096) return;
  int k   = idx & 31;
  int lr  = (idx >> 5) & 15;
  int oct = idx >> 9;
  int oc  = oct * 16 + lr;
  float v = (k < 25) ? w1[oc * 25 + k] : 0.f;
  w1b[idx] = __float2bfloat16(v);
}

// ---------------------------------------------------------------------------
// Fused conv1 (MFMA) -> h1 LDS bf16 swizzled -> conv2 (MFMA, 4-wave K-split)
// -> BN2+LReLU+L2norm -> db.   (unchanged from round 5)
// ---------------------------------------------------------------------------
__global__ __launch_bounds__(256) void k_conv(
    const float* __restrict__ x,
    const __hip_bfloat16* __restrict__ w1bh, const float* __restrict__ b1,
    const float* __restrict__ g1,  const float* __restrict__ be1,
    const float* __restrict__ mn1, const float* __restrict__ vr1,
    const __hip_bfloat16* __restrict__ w2bh, const float* __restrict__ b2,
    const float* __restrict__ g2,  const float* __restrict__ be2,
    const float* __restrict__ mn2, const float* __restrict__ vr2,
    __hip_bfloat16* __restrict__ db) {
  __shared__ float xs[1024];
  __shared__ float bn2s[128];
  __shared__ float bn1a[128], bn1b[128];
  __shared__ float nrm[4];
  __shared__ __align__(16) __hip_bfloat16 h1s[197 * 128];

  const int t    = threadIdx.x;
  const int img  = blockIdx.x;
  const int lane = t & 63;
  const int wv   = t >> 6;
  const int lr   = lane & 15;
  const int kg   = lane >> 4;
  const short* w2b = (const short*)w2bh;
  const short* w1b = (const short*)w1bh;

  for (int i = t; i < 1024; i += 256) xs[i] = 0.f;
  if (t < 64) {
    float a2 = g2[t] * rsqrtf(vr2[t] + BN_EPS);
    bn2s[t]      = a2;
    bn2s[64 + t] = b2[t] * a2 + be2[t] - mn2[t] * a2;
    ((unsigned*)(h1s + 196 * 128))[t] = 0u;
  }
  if (t < 128) {
    float a1 = g1[t] * rsqrtf(vr1[t] + BN_EPS);
    bn1a[t] = a1;
    bn1b[t] = b1[t] * a1 + be1[t] - mn1[t] * a1;
  }
  __syncthreads();
  const float* xi = x + (size_t)img * 784;
  for (int i = t; i < 784; i += 256) {
    int yy = i / 28, xx = i % 28;
    xs[(yy + 2) * 32 + (xx + 2)] = xi[i];
  }
  __syncthreads();

  {
    bf16x8 a0 = *(const bf16x8*)(w1b + (2 * wv) * 512 + lr * 32 + kg * 8);
    bf16x8 a1 = *(const bf16x8*)(w1b + (2 * wv + 1) * 512 + lr * 32 + kg * 8);
    for (int pt = 0; pt < 13; ++pt) {
      const int px  = pt * 16 + lr;
      const int pxc = (px < 196) ? px : 195;
      const int oy  = pxc / 14, ox = pxc - 14 * (pxc / 14);
      const float* xb = xs + (2 * oy) * 32 + 2 * ox;
      short bs[8];
#pragma unroll
      for (int j = 0; j < 8; ++j) {
        int k   = kg * 8 + j;
        int tap = (k < 25) ? k : 0;
        int kh  = tap / 5, kw = tap - 5 * (tap / 5);
        bs[j] = f2b(xb[kh * 32 + kw]);
      }
      bf16x8 b;
#pragma unroll
      for (int j = 0; j < 8; ++j) b[j] = bs[j];
      f32x4 c0 = {0.f, 0.f, 0.f, 0.f}, c1 = {0.f, 0.f, 0.f, 0.f};
      c0 = __builtin_amdgcn_mfma_f32_16x16x32_bf16(a0, b, c0, 0, 0, 0);
      c1 = __builtin_amdgcn_mfma_f32_16x16x32_bf16(a1, b, c1, 0, 0, 0);
      if (px < 196) {
        const int swz = (px & 7) << 4;
        unsigned w0lo, w0hi, w1lo, w1hi;
        {
          float v[4], u[4];
#pragma unroll
          for (int r = 0; r < 4; ++r) {
            int oc = wv * 32 + kg * 4 + r;
            float h = c0[r] * bn1a[oc] + bn1b[oc];
            v[r] = (h >= 0.f) ? h : SLOPE * h;
            int oc2 = oc + 16;
            float h2 = c1[r] * bn1a[oc2] + bn1b[oc2];
            u[r] = (h2 >= 0.f) ? h2 : SLOPE * h2;
          }
          w0lo = (unsigned)(unsigned short)f2b(v[0]) |
                 ((unsigned)(unsigned short)f2b(v[1]) << 16);
          w0hi = (unsigned)(unsigned short)f2b(v[2]) |
                 ((unsigned)(unsigned short)f2b(v[3]) << 16);
          w1lo = (unsigned)(unsigned short)f2b(u[0]) |
                 ((unsigned)(unsigned short)f2b(u[1]) << 16);
          w1hi = (unsigned)(unsigned short)f2b(u[2]) |
                 ((unsigned)(unsigned short)f2b(u[3]) << 16);
        }
        char* base = (char*)h1s + px * 256;
        const int o0 = ((wv * 32 + kg * 4) * 2) ^ swz;
        const int o1 = ((wv * 32 + 16 + kg * 4) * 2) ^ swz;
        *(uint2*)(base + o0) = make_uint2(w0lo, w0hi);
        *(uint2*)(base + o1) = make_uint2(w1lo, w1hi);
      }
    }
  }
  __syncthreads();

  const int woff  = lr * 32 + kg * 8;
  const int kgoff = kg << 4;
  int pxA[4], oyA[4], oxA[4];
#pragma unroll
  for (int pt = 0; pt < 4; ++pt) {
    int p = pt * 16 + lr;
    pxA[pt] = p;
    oyA[pt] = p / 7;
    oxA[pt] = p - 7 * oyA[pt];
  }

  f32x4 acc[4][4];
#pragma unroll
  for (int oct = 0; oct < 4; ++oct)
#pragma unroll
    for (int pt = 0; pt < 4; ++pt) acc[oct][pt] = (f32x4){0.f, 0.f, 0.f, 0.f};

  const int s0 = 25 * wv, s1e = s0 + 25;
  int curtap = -1;
  int rowB[4], rowS[4];

  auto loadk = [&](int kk, bf16x8* areg, bf16x8* breg) {
    int tap = kk >> 2;
    if (tap != curtap) {
      curtap = tap;
      int kh = tap / 5, kw = tap - 5 * (tap / 5);
#pragma unroll
      for (int pt = 0; pt < 4; ++pt) {
        int iy = 2 * oyA[pt] - 2 + kh;
        int ix = 2 * oxA[pt] - 2 + kw;
        bool val = (pxA[pt] < 49) & ((unsigned)iy < 14u) & ((unsigned)ix < 14u);
        int ip = val ? iy * 14 + ix : 196;
        rowB[pt] = ip * 256;
        rowS[pt] = (ip & 7) << 4;
      }
    }
    int c01 = (kk & 3) << 6;
#pragma unroll
    for (int oct = 0; oct < 4; ++oct)
      areg[oct] = *(const bf16x8*)(w2b + ((oct * 100 + kk) << 9) + woff);
#pragma unroll
    for (int pt = 0; pt < 4; ++pt)
      breg[pt] = *(const bf16x8*)((const char*)h1s + rowB[pt] +
                                  ((c01 | kgoff) ^ rowS[pt]));
  };

  bf16x8 a[4], b[4], an[4], bn_[4];
  loadk(s0, a, b);
  for (int kk = s0; kk < s1e; ++kk) {
    if (kk + 1 < s1e) loadk(kk + 1, an, bn_);
#pragma unroll
    for (int oct = 0; oct < 4; ++oct)
#pragma unroll
      for (int pt = 0; pt < 4; ++pt)
        acc[oct][pt] = __builtin_amdgcn_mfma_f32_16x16x32_bf16(a[oct], b[pt],
                                                               acc[oct][pt], 0, 0, 0);
#pragma unroll
    for (int q = 0; q < 4; ++q) { a[q] = an[q]; b[q] = bn_[q]; }
  }
  __syncthreads();

  float* red = (float*)h1s;
  if (wv != 0) {
#pragma unroll
    for (int oct = 0; oct < 4; ++oct)
#pragma unroll
      for (int pt = 0; pt < 4; ++pt)
#pragma unroll
        for (int r = 0; r < 4; ++r)
          red[(wv - 1) * 4096 + ((oct * 4 + pt) * 4 + r) * 64 + lane] =
              acc[oct][pt][r];
  }
  __syncthreads();
  if (wv == 0) {
#pragma unroll
    for (int oct = 0; oct < 4; ++oct)
#pragma unroll
      for (int pt = 0; pt < 4; ++pt)
#pragma unroll
        for (int r = 0; r < 4; ++r) {
          const int i = (oct * 4 + pt) * 4 + r;
          float v = acc[oct][pt][r] + red[i * 64 + lane] +
                    red[4096 + i * 64 + lane] + red[8192 + i * 64 + lane];
          red[i * 64 + lane] = v;
        }
  }
  __syncthreads();

  float outv[16];
  float ss = 0.f;
#pragma unroll
  for (int pt = 0; pt < 4; ++pt) {
#pragma unroll
    for (int r = 0; r < 4; ++r) {
      const int i = ((wv * 4 + pt) * 4 + r);
      float v = red[i * 64 + lane];
      const int oc = wv * 16 + kg * 4 + r;
      v = v * bn2s[oc] + bn2s[64 + oc];
      v = (v >= 0.f) ? v : SLOPE * v;
      outv[pt * 4 + r] = v;
      if (pxA[pt] < 49) ss += v * v;
    }
  }
#pragma unroll
  for (int m = 1; m < 64; m <<= 1) ss += __shfl_xor(ss, m, 64);
  if (lane == 0) nrm[wv] = ss;
  __syncthreads();
  const float invn = rsqrtf(nrm[0] + nrm[1] + nrm[2] + nrm[3]);
  __hip_bfloat16* dro = db + (size_t)img * DDIM;
#pragma unroll
  for (int pt = 0; pt < 4; ++pt) {
    if (pxA[pt] < 49) {
#pragma unroll
      for (int r = 0; r < 4; ++r) {
        const int oc = wv * 16 + kg * 4 + r;
        dro[oc * 49 + pxA[pt]] = __float2bfloat16(outv[pt * 4 + r] * invn);
      }
    }
  }
}

// ---------------------------------------------------------------------------
// 64x64 tiled transpose: dT[d][img] = db[img][d]  (d < 3136; pad rows untouched)
// ---------------------------------------------------------------------------
__global__ __launch_bounds__(256) void k_tr(const __hip_bfloat16* __restrict__ dbh,
                                            __hip_bfloat16* __restrict__ dTh) {
  __shared__ short tile[64][72];
  const int t   = threadIdx.x;
  const int i   = t >> 2;
  const int seg = t & 3;
  const size_t img0 = (size_t)blockIdx.x * 64;
  const size_t d0   = (size_t)blockIdx.y * 64;
  const short* src = (const short*)dbh + (img0 + i) * DDIM + d0 + seg * 16;
  bf16x8 v0 = *(const bf16x8*)src;
  bf16x8 v1 = *(const bf16x8*)(src + 8);
  *(bf16x8*)&tile[i][seg * 16]     = v0;
  *(bf16x8*)&tile[i][seg * 16 + 8] = v1;
  __syncthreads();
  short tmp[16];
#pragma unroll
  for (int k = 0; k < 16; ++k) tmp[k] = tile[seg * 16 + k][i];
  short* dst = (short*)dTh + (d0 + i) * 8192 + img0 + seg * 16;
  *(bf16x8*)dst       = *(bf16x8*)tmp;
  *(bf16x8*)(dst + 8) = *((bf16x8*)tmp + 1);
}

// ---------------------------------------------------------------------------
__global__ __launch_bounds__(256) void k_muinit(const float* __restrict__ mu0,
                                                __hip_bfloat16* __restrict__ mub) {
  int idx = blockIdx.x * 256 + threadIdx.x;
  if (idx >= 112 * DDIM) return;
  int j = idx / DDIM, d = idx - j * DDIM;
  float v = (j < 100) ? mu0[j * DDIM + d] : 0.f;
  mub[idx] = __float2bfloat16(v);
}

// ---------------------------------------------------------------------------
// Fused dist (MFMA) + softmax + cluster_r.
// Block: 512 thr = 8 waves over 32 rows: wave wv -> rowgroup rg=wv>>2 (16 rows),
// K-split ks=wv&3 (98/4 K-steps). Tail: all 8 waves finish 4 rows each.
// ---------------------------------------------------------------------------
__global__ __launch_bounds__(512) void k_dsm(
    const __hip_bfloat16* __restrict__ data,
    const __hip_bfloat16* __restrict__ mu,
    __hip_bfloat16* __restrict__ rT,          // [112][8192]
    float* __restrict__ cr,                   // [128] slot for this iter
    float* __restrict__ outr,                 // final: [8192][100]
    float* __restrict__ outd,                 // final: [8192][100]
    int final_flag) {
  __shared__ float red[8][64][29];            // 59392 B
  const int t    = threadIdx.x;
  const int lane = t & 63;
  const int wv   = t >> 6;                    // 0..7
  const int rg   = wv >> 2;                   // rowgroup 0/1
  const int ks   = wv & 3;                    // K-split 0..3
  const int rowbase = blockIdx.x * 32;
  const int s0 = (98 * ks) >> 2;
  const int s1 = (98 * (ks + 1)) >> 2;
  const int lr = lane & 15;
  const int kg = lane >> 4;

  const __hip_bfloat16* arow = data + (size_t)(rowbase + rg * 16 + lr) * DDIM + kg * 8;
  const __hip_bfloat16* brow = mu + (size_t)lr * DDIM + kg * 8;

  f32x4 acc[7];
#pragma unroll
  for (int i = 0; i < 7; ++i) acc[i] = (f32x4){0.f, 0.f, 0.f, 0.f};

  bf16x8 a, b[7], an, bn_[7];
  {
    const int k0 = s0 * 32;
    a = *(const bf16x8*)(arow + k0);
#pragma unroll
    for (int tl = 0; tl < 7; ++tl)
      b[tl] = *(const bf16x8*)(brow + (size_t)tl * 16 * DDIM + k0);
  }
  for (int s = s0; s < s1; ++s) {
    if (s + 1 < s1) {
      const int k1 = (s + 1) * 32;
      an = *(const bf16x8*)(arow + k1);
#pragma unroll
      for (int tl = 0; tl < 7; ++tl)
        bn_[tl] = *(const bf16x8*)(brow + (size_t)tl * 16 * DDIM + k1);
    }
#pragma unroll
    for (int tl = 0; tl < 7; ++tl)
      acc[tl] = __builtin_amdgcn_mfma_f32_16x16x32_bf16(a, b[tl], acc[tl], 0, 0, 0);
    a = an;
#pragma unroll
    for (int tl = 0; tl < 7; ++tl) b[tl] = bn_[tl];
  }

#pragma unroll
  for (int tl = 0; tl < 7; ++tl)
#pragma unroll
    for (int r = 0; r < 4; ++r) red[wv][lane][tl * 4 + r] = acc[tl][r];
  __syncthreads();

  // tail: wave wv owns block-rows [4wv, 4wv+4); lane>>4 picks the row.
  const int r_   = lane >> 4;                 // row within the wave's 4
  const int kg_t = wv & 3;                    // source kg group
  const int rg_t = wv >> 2;                   // source rowgroup
  const int grow = rowbase + 4 * wv + r_;     // global row
  float v[7];
#pragma unroll
  for (int tl = 0; tl < 7; ++tl) {
    float s = 0.f;
#pragma unroll
    for (int k2 = 0; k2 < 4; ++k2)
      s += red[rg_t * 4 + k2][kg_t * 16 + lr][tl * 4 + r_];
    v[tl] = s;
  }

  if (final_flag) {
#pragma unroll
    for (int tl = 0; tl < 7; ++tl) {
      const int col = tl * 16 + lr;
      if (col < 100) outd[(size_t)grow * 100 + col] = v[tl];
    }
  }

  // softmax over the row's 112 cols (row spans one 16-lane group)
  float m = -1e30f;
#pragma unroll
  for (int tl = 0; tl < 7; ++tl) {
    const bool valid = (tl < 6) || (lr < 4);
    m = fmaxf(m, valid ? v[tl] : -1e30f);
  }
  m = fmaxf(m, __shfl_xor(m, 1, 64));
  m = fmaxf(m, __shfl_xor(m, 2, 64));
  m = fmaxf(m, __shfl_xor(m, 4, 64));
  m = fmaxf(m, __shfl_xor(m, 8, 64));
  float e[7];
  float s = 0.f;
#pragma unroll
  for (int tl = 0; tl < 7; ++tl) {
    const bool valid = (tl < 6) || (lr < 4);
    e[tl] = valid ? __expf(TEMP * (v[tl] - m)) : 0.f;
    s += e[tl];
  }
  s += __shfl_xor(s, 1, 64);
  s += __shfl_xor(s, 2, 64);
  s += __shfl_xor(s, 4, 64);
  s += __shfl_xor(s, 8, 64);
  const float inv = 1.f / s;
#pragma unroll
  for (int tl = 0; tl < 7; ++tl) e[tl] *= inv;

  if (final_flag) {
#pragma unroll
    for (int tl = 0; tl < 7; ++tl) {
      const int col = tl * 16 + lr;
      if (col < 100) outr[(size_t)grow * 100 + col] = e[tl];
    }
    return;
  }

#pragma unroll
  for (int tl = 0; tl < 7; ++tl) {
    const int col = tl * 16 + lr;
    if (col < 100)
      rT[(size_t)col * 8192 + grow] = __float2bfloat16(e[tl]);
  }
  // cluster_r: sum the wave's 4 rows, then one atomic per col per wave
  float cs[7];
#pragma unroll
  for (int tl = 0; tl < 7; ++tl) {
    float c2 = e[tl];
    c2 += __shfl_xor(c2, 16, 64);
    c2 += __shfl_xor(c2, 32, 64);
    cs[tl] = c2;
  }
  if (lane < 16) {
#pragma unroll
    for (int tl = 0; tl < 7; ++tl) {
      const int col = tl * 16 + lane;
      if (col < 100) atomicAdd(cr + col, cs[tl]);
    }
  }
}

// ---------------------------------------------------------------------------
// cms[split][d][j] (bf16) = partial dataT @ rT over K-chunk of 512.
// grid (25, 16); block 256 thr = 4 waves; wave handles 2 m-tiles (32 rows),
// block M=128 (d padded to 3200).
// ---------------------------------------------------------------------------
__global__ __launch_bounds__(256) void k_mu(
    const __hip_bfloat16* __restrict__ dataT,  // [3200][8192]
    const __hip_bfloat16* __restrict__ rT,     // [112][8192]
    __hip_bfloat16* __restrict__ cms) {        // [16][3200][112]
  const int t    = threadIdx.x;
  const int lane = t & 63;
  const int wv   = t >> 6;
  const int mbase = blockIdx.x * 128 + wv * 32;
  const int kbase = blockIdx.y * 512;
  const int lr = lane & 15;
  const int kg = lane >> 4;

  const __hip_bfloat16* arow0 = dataT + (size_t)(mbase + lr) * 8192 + kbase + kg * 8;
  const __hip_bfloat16* arow1 = arow0 + (size_t)16 * 8192;
  const __hip_bfloat16* brow  = rT + (size_t)lr * 8192 + kbase + kg * 8;

  f32x4 acc[2][7];
#pragma unroll
  for (int mt = 0; mt < 2; ++mt)
#pragma unroll
    for (int i = 0; i < 7; ++i) acc[mt][i] = (f32x4){0.f, 0.f, 0.f, 0.f};

  bf16x8 a0, a1, b[7], a0n, a1n, bn_[7];
  a0 = *(const bf16x8*)(arow0);
  a1 = *(const bf16x8*)(arow1);
#pragma unroll
  for (int tl = 0; tl < 7; ++tl)
    b[tl] = *(const bf16x8*)(brow + (size_t)tl * 16 * 8192);
  for (int s = 0; s < 16; ++s) {
    if (s + 1 < 16) {
      const int k1 = (s + 1) * 32;
      a0n = *(const bf16x8*)(arow0 + k1);
      a1n = *(const bf16x8*)(arow1 + k1);
#pragma unroll
      for (int tl = 0; tl < 7; ++tl)
        bn_[tl] = *(const bf16x8*)(brow + (size_t)tl * 16 * 8192 + k1);
    }
#pragma unroll
    for (int tl = 0; tl < 7; ++tl) {
      acc[0][tl] = __builtin_amdgcn_mfma_f32_16x16x32_bf16(a0, b[tl], acc[0][tl], 0, 0, 0);
      acc[1][tl] = __builtin_amdgcn_mfma_f32_16x16x32_bf16(a1, b[tl], acc[1][tl], 0, 0, 0);
    }
    a0 = a0n; a1 = a1n;
#pragma unroll
    for (int tl = 0; tl < 7; ++tl) b[tl] = bn_[tl];
  }

  __hip_bfloat16* dst = cms + (size_t)blockIdx.y * (3200u * 112u);
#pragma unroll
  for (int mt = 0; mt < 2; ++mt) {
#pragma unroll
    for (int tl = 0; tl < 7; ++tl) {
      const int col = tl * 16 + lr;
#pragma unroll
      for (int r = 0; r < 4; ++r)
        dst[(size_t)(mbase + mt * 16 + kg * 4 + r) * 112 + col] =
            __float2bfloat16(acc[mt][tl][r]);
    }
  }
}

// ---------------------------------------------------------------------------
// Reduce 16 cms splits + LDS transpose + divide by cr. grid 196 (16 d each).
// ---------------------------------------------------------------------------
__global__ __launch_bounds__(256) void k_upd(const __hip_bfloat16* __restrict__ cms,
                                             const float* __restrict__ cr,
                                             float* __restrict__ muf,
                                             __hip_bfloat16* __restrict__ mub) {
  __shared__ float tile[16][113];
  const int t  = threadIdx.x;
  const int d0 = blockIdx.x * 16;
  for (int e = t; e < 16 * 112; e += 256) {
    int dd = e / 112, jj = e - dd * 112;
    const __hip_bfloat16* p = cms + (size_t)(d0 + dd) * 112 + jj;
    float v = 0.f;
#pragma unroll
    for (int s2 = 0; s2 < 16; ++s2)
      v += __bfloat162float(p[(size_t)s2 * (3200u * 112u)]);
    tile[dd][jj] = v;
  }
  __syncthreads();
  for (int e = t; e < 100 * 16; e += 256) {
    int jj = e >> 4, dd = e & 15;
    float v = tile[dd][jj] / cr[jj];
    muf[(size_t)jj * DDIM + d0 + dd] = v;
    mub[(size_t)jj * DDIM + d0 + dd] = __float2bfloat16(v);
  }
}

// ---------------------------------------------------------------------------
extern "C" void kernel_launch(void* const* d_in, const int* in_sizes, int n_in,
                              void* d_out, int out_size, void* d_ws, size_t ws_size,
                              hipStream_t stream) {
  const float* x   = (const float*)d_in[0];
  const float* w1  = (const float*)d_in[1];
  const float* b1  = (const float*)d_in[2];
  const float* g1  = (const float*)d_in[3];
  const float* be1 = (const float*)d_in[4];
  const float* mn1 = (const float*)d_in[5];
  const float* vr1 = (const float*)d_in[6];
  const float* w2  = (const float*)d_in[7];
  const float* b2  = (const float*)d_in[8];
  const float* g2  = (const float*)d_in[9];
  const float* be2 = (const float*)d_in[10];
  const float* mn2 = (const float*)d_in[11];
  const float* vr2 = (const float*)d_in[12];
  const float* mu0 = (const float*)d_in[13];

  float* ws = (float*)d_ws;
  __hip_bfloat16* w2b = (__hip_bfloat16*)(ws + W2B_OFF);
  __hip_bfloat16* w1b = (__hip_bfloat16*)(ws + W1B_OFF);
  __hip_bfloat16* db  = (__hip_bfloat16*)(ws + DB_OFF);
  __hip_bfloat16* dT  = (__hip_bfloat16*)(ws + DT_OFF);
  __hip_bfloat16* mub = (__hip_bfloat16*)(ws + MUB_OFF);
  float*          muf = ws + MUF_OFF;
  __hip_bfloat16* cms = (__hip_bfloat16*)(ws + CMS_OFF);
  __hip_bfloat16* rT  = (__hip_bfloat16*)(ws + RT_OFF);
  float*          crb = ws + CR_OFF;               // [12][128]
  float*          out = (float*)d_out;

  k_w2b<<<800, 256, 0, stream>>>(w2, w2b);
  k_w1b<<<16, 256, 0, stream>>>(w1, w1b);
  k_conv<<<8192, 256, 0, stream>>>(x, w1b, b1, g1, be1, mn1, vr1,
                                   w2b, b2, g2, be2, mn2, vr2, db);
  k_tr<<<dim3(128, 49), 256, 0, stream>>>(db, dT);
  k_muinit<<<(112 * DDIM + 255) / 256, 256, 0, stream>>>(mu0, mub);
  hipMemsetAsync(rT + (size_t)100 * 8192, 0, 12 * 8192 * sizeof(__hip_bfloat16),
                 stream);
  hipMemsetAsync(crb, 0, 12 * 128 * sizeof(float), stream);

  for (int it = 0; it < 11; ++it) {
    float* cr = crb + it * 128;
    k_dsm<<<256, 512, 0, stream>>>(db, mub, rT, cr, nullptr, nullptr, 0);
    k_mu<<<dim3(25, 16), 256, 0, stream>>>(dT, rT, cms);
    k_upd<<<196, 256, 0, stream>>>(cms, cr, muf, mub);
  }

  k_dsm<<<256, 512, 0, stream>>>(db, mub, rT, crb + 11 * 128,
                                 out + 313600, out + 1132800, 1);
  hipMemcpyAsync(out, muf, (size_t)MUF_SZ * sizeof(float),
                 hipMemcpyDeviceToDevice, stream);
}